// Round 6
// baseline (1450.674 us; speedup 1.0000x reference)
//
#include <hip/hip_runtime.h>
#include <stdint.h>

#define BB 4
#define TT 2048
#define SS 2048
#define EE 512
#define HH 8
#define DH 64
#define NEG_INF_F (-1e30f)

// ---------------------------------------------------------------------------
// Generic projection GEMM: C[M,512] = (A[M,512] @ W[512,512] + bias) * alpha
// BM=128, BN=64, BK=16, 256 threads, 8x4 per thread.
// ---------------------------------------------------------------------------
__global__ __launch_bounds__(256) void proj_gemm(const float* __restrict__ A,
        const float* __restrict__ W, const float* __restrict__ bias,
        float* __restrict__ C, float alpha) {
    const int K = EE, N = EE;
    __shared__ float As[16][128 + 4];   // transposed: As[k][m]
    __shared__ float Bs[16][64 + 4];
    const int tid = threadIdx.x;
    const int tx = tid & 15;            // col group: 4 cols each
    const int ty = tid >> 4;            // row group: 8 rows each
    const int bm = blockIdx.y * 128;
    const int bn = blockIdx.x * 64;
    float acc[8][4] = {};
    for (int k0 = 0; k0 < K; k0 += 16) {
        // A tile 128x16 -> As[k][m] (transposed store)
        #pragma unroll
        for (int j = 0; j < 2; ++j) {
            int f = tid + 256 * j;      // 512 float4 total
            int row = f >> 2;           // 4 float4 per row
            int c4 = f & 3;
            float4 v = *reinterpret_cast<const float4*>(
                &A[(size_t)(bm + row) * K + k0 + c4 * 4]);
            As[c4 * 4 + 0][row] = v.x;
            As[c4 * 4 + 1][row] = v.y;
            As[c4 * 4 + 2][row] = v.z;
            As[c4 * 4 + 3][row] = v.w;
        }
        // B tile 16x64
        {
            int row = tid >> 4;         // 16 rows
            int c4 = tid & 15;          // 16 float4 per row
            float4 v = *reinterpret_cast<const float4*>(
                &W[(size_t)(k0 + row) * N + bn + c4 * 4]);
            *reinterpret_cast<float4*>(&Bs[row][c4 * 4]) = v;
        }
        __syncthreads();
        #pragma unroll
        for (int kk = 0; kk < 16; ++kk) {
            float a[8], b[4];
            #pragma unroll
            for (int i = 0; i < 8; ++i) a[i] = As[kk][ty * 8 + i];
            #pragma unroll
            for (int j = 0; j < 4; ++j) b[j] = Bs[kk][tx * 4 + j];
            #pragma unroll
            for (int i = 0; i < 8; ++i)
                #pragma unroll
                for (int j = 0; j < 4; ++j)
                    acc[i][j] = fmaf(a[i], b[j], acc[i][j]);
        }
        __syncthreads();
    }
    #pragma unroll
    for (int i = 0; i < 8; ++i) {
        float4 o;
        o.x = (acc[i][0] + bias[bn + tx * 4 + 0]) * alpha;
        o.y = (acc[i][1] + bias[bn + tx * 4 + 1]) * alpha;
        o.z = (acc[i][2] + bias[bn + tx * 4 + 2]) * alpha;
        o.w = (acc[i][3] + bias[bn + tx * 4 + 3]) * alpha;
        *reinterpret_cast<float4*>(
            &C[(size_t)(bm + ty * 8 + i) * N + bn + tx * 4]) = o;
    }
}

// ---------------------------------------------------------------------------
// scores[bh, t, s] = sum_d q[b,t,h*64+d] * k[b,s,h*64+d]  (+ masking)
// 64x64 output tile per block, K=64 fully staged in LDS (transposed).
// ---------------------------------------------------------------------------
__global__ __launch_bounds__(256) void scores_kernel(const float* __restrict__ q,
        const float* __restrict__ k, const uint8_t* __restrict__ am,
        const uint8_t* __restrict__ kpm, float* __restrict__ Sc) {
    const int bh = blockIdx.z;
    const int b = bh >> 3, h = bh & 7;
    const int t0 = blockIdx.y * 64;
    const int s0 = blockIdx.x * 64;
    __shared__ float Qs[DH][64 + 4];    // [d][t]
    __shared__ float Ks[DH][64 + 4];    // [d][s]
    const int tid = threadIdx.x;
    #pragma unroll
    for (int j = 0; j < 4; ++j) {
        int f = tid + 256 * j;          // 1024 float4 per tile
        int row = f >> 4;               // 16 float4 per row
        int c4 = f & 15;
        float4 vq = *reinterpret_cast<const float4*>(
            &q[(size_t)(b * TT + t0 + row) * EE + h * DH + c4 * 4]);
        Qs[c4 * 4 + 0][row] = vq.x; Qs[c4 * 4 + 1][row] = vq.y;
        Qs[c4 * 4 + 2][row] = vq.z; Qs[c4 * 4 + 3][row] = vq.w;
        float4 vk = *reinterpret_cast<const float4*>(
            &k[(size_t)(b * SS + s0 + row) * EE + h * DH + c4 * 4]);
        Ks[c4 * 4 + 0][row] = vk.x; Ks[c4 * 4 + 1][row] = vk.y;
        Ks[c4 * 4 + 2][row] = vk.z; Ks[c4 * 4 + 3][row] = vk.w;
    }
    __syncthreads();
    const int tx = tid & 15, ty = tid >> 4;   // 4 cols, 4 rows per thread
    float acc[4][4] = {};
    #pragma unroll 8
    for (int d = 0; d < DH; ++d) {
        float a[4], bv[4];
        #pragma unroll
        for (int i = 0; i < 4; ++i) a[i] = Qs[d][ty * 4 + i];
        #pragma unroll
        for (int j = 0; j < 4; ++j) bv[j] = Ks[d][tx * 4 + j];
        #pragma unroll
        for (int i = 0; i < 4; ++i)
            #pragma unroll
            for (int j = 0; j < 4; ++j)
                acc[i][j] = fmaf(a[i], bv[j], acc[i][j]);
    }
    uchar4 kv = *reinterpret_cast<const uchar4*>(&kpm[b * SS + s0 + tx * 4]);
    #pragma unroll
    for (int i = 0; i < 4; ++i) {
        int t = t0 + ty * 4 + i;
        uchar4 amv = *reinterpret_cast<const uchar4*>(
            &am[(size_t)t * SS + s0 + tx * 4]);
        float4 o;
        o.x = (amv.x | kv.x) ? NEG_INF_F : acc[i][0];
        o.y = (amv.y | kv.y) ? NEG_INF_F : acc[i][1];
        o.z = (amv.z | kv.z) ? NEG_INF_F : acc[i][2];
        o.w = (amv.w | kv.w) ? NEG_INF_F : acc[i][3];
        *reinterpret_cast<float4*>(
            &Sc[((size_t)bh * TT + t) * SS + s0 + tx * 4]) = o;
    }
}

// ---------------------------------------------------------------------------
// In-place row softmax over S=2048. One block (256 thr) per row; row held in
// registers (8 floats/thread), one global read + one global write.
// ---------------------------------------------------------------------------
__device__ __forceinline__ float wred_max(float v) {
    #pragma unroll
    for (int off = 32; off > 0; off >>= 1) v = fmaxf(v, __shfl_xor(v, off));
    return v;
}
__device__ __forceinline__ float wred_sum(float v) {
    #pragma unroll
    for (int off = 32; off > 0; off >>= 1) v += __shfl_xor(v, off);
    return v;
}

__global__ __launch_bounds__(256) void softmax_kernel(float* __restrict__ P) {
    const size_t base = (size_t)blockIdx.x * SS;
    const int tid = threadIdx.x;
    float4 x0 = *reinterpret_cast<const float4*>(&P[base + (size_t)tid * 4]);
    float4 x1 = *reinterpret_cast<const float4*>(&P[base + (size_t)(tid + 256) * 4]);
    float m = fmaxf(fmaxf(fmaxf(x0.x, x0.y), fmaxf(x0.z, x0.w)),
                    fmaxf(fmaxf(x1.x, x1.y), fmaxf(x1.z, x1.w)));
    m = wred_max(m);
    __shared__ float rmax[4];
    __shared__ float rsum[4];
    const int wid = tid >> 6, lane = tid & 63;
    if (lane == 0) rmax[wid] = m;
    __syncthreads();
    m = fmaxf(fmaxf(rmax[0], rmax[1]), fmaxf(rmax[2], rmax[3]));
    x0.x = __expf(x0.x - m); x0.y = __expf(x0.y - m);
    x0.z = __expf(x0.z - m); x0.w = __expf(x0.w - m);
    x1.x = __expf(x1.x - m); x1.y = __expf(x1.y - m);
    x1.z = __expf(x1.z - m); x1.w = __expf(x1.w - m);
    float s = x0.x + x0.y + x0.z + x0.w + x1.x + x1.y + x1.z + x1.w;
    s = wred_sum(s);
    if (lane == 0) rsum[wid] = s;
    __syncthreads();
    s = rsum[0] + rsum[1] + rsum[2] + rsum[3];
    const float inv = 1.0f / s;
    x0.x *= inv; x0.y *= inv; x0.z *= inv; x0.w *= inv;
    x1.x *= inv; x1.y *= inv; x1.z *= inv; x1.w *= inv;
    *reinterpret_cast<float4*>(&P[base + (size_t)tid * 4]) = x0;
    *reinterpret_cast<float4*>(&P[base + (size_t)(tid + 256) * 4]) = x1;
}

// ---------------------------------------------------------------------------
// ctx[b, t, h*64+d] = sum_s P[bh,t,s] * v[b,s,h*64+d]
// BM=128 (t), BN=64 (=Dh, full), BK=16; 256 threads, 8x4 per thread.
// ---------------------------------------------------------------------------
__global__ __launch_bounds__(256) void pv_kernel(const float* __restrict__ P,
        const float* __restrict__ v, float* __restrict__ ctx) {
    const int bh = blockIdx.y;
    const int b = bh >> 3, h = bh & 7;
    const int t0 = blockIdx.x * 128;
    __shared__ float Ps[16][128 + 4];   // [s][t] (transposed)
    __shared__ float Vs[16][64 + 4];    // [s][d]
    const int tid = threadIdx.x;
    const int tx = tid & 15, ty = tid >> 4;
    float acc[8][4] = {};
    for (int s0 = 0; s0 < SS; s0 += 16) {
        #pragma unroll
        for (int j = 0; j < 2; ++j) {
            int f = tid + 256 * j;      // 512 float4
            int row = f >> 2;           // 4 float4 per row
            int c4 = f & 3;
            float4 pv = *reinterpret_cast<const float4*>(
                &P[((size_t)bh * TT + t0 + row) * SS + s0 + c4 * 4]);
            Ps[c4 * 4 + 0][row] = pv.x; Ps[c4 * 4 + 1][row] = pv.y;
            Ps[c4 * 4 + 2][row] = pv.z; Ps[c4 * 4 + 3][row] = pv.w;
        }
        {
            int row = tid >> 4, c4 = tid & 15;
            float4 vv = *reinterpret_cast<const float4*>(
                &v[(size_t)(b * SS + s0 + row) * EE + h * DH + c4 * 4]);
            *reinterpret_cast<float4*>(&Vs[row][c4 * 4]) = vv;
        }
        __syncthreads();
        #pragma unroll
        for (int kk = 0; kk < 16; ++kk) {
            float a[8], bv[4];
            #pragma unroll
            for (int i = 0; i < 8; ++i) a[i] = Ps[kk][ty * 8 + i];
            #pragma unroll
            for (int j = 0; j < 4; ++j) bv[j] = Vs[kk][tx * 4 + j];
            #pragma unroll
            for (int i = 0; i < 8; ++i)
                #pragma unroll
                for (int j = 0; j < 4; ++j)
                    acc[i][j] = fmaf(a[i], bv[j], acc[i][j]);
        }
        __syncthreads();
    }
    #pragma unroll
    for (int i = 0; i < 8; ++i) {
        float4 o = make_float4(acc[i][0], acc[i][1], acc[i][2], acc[i][3]);
        *reinterpret_cast<float4*>(
            &ctx[(size_t)(b * TT + t0 + ty * 8 + i) * EE + h * DH + tx * 4]) = o;
    }
}

// ---------------------------------------------------------------------------
extern "C" void kernel_launch(void* const* d_in, const int* in_sizes, int n_in,
                              void* d_out, int out_size, void* d_ws, size_t ws_size,
                              hipStream_t stream) {
    const float*   query = (const float*)d_in[0];
    const float*   key   = (const float*)d_in[1];
    const float*   value = (const float*)d_in[2];
    const uint8_t* kpm   = (const uint8_t*)d_in[3];
    const uint8_t* am    = (const uint8_t*)d_in[4];
    const float* Wq = (const float*)d_in[5];  const float* bq = (const float*)d_in[6];
    const float* Wk = (const float*)d_in[7];  const float* bk = (const float*)d_in[8];
    const float* Wv = (const float*)d_in[9];  const float* bv = (const float*)d_in[10];
    const float* Wo = (const float*)d_in[11]; const float* bo = (const float*)d_in[12];

    float* out   = (float*)d_out;
    const size_t BTE = (size_t)BB * TT * EE;           // 4,194,304
    float* attnW = out + BTE;                          // [B,H,T,S]
    float* ws  = (float*)d_ws;
    float* qp  = ws;                                   // [B,T,E]
    float* kp  = ws + BTE;                             // [B,S,E]
    float* vp  = ws + 2 * BTE;                         // [B,S,E]
    float* ctx = qp;  // alias: qp is dead after scores_kernel (stream-ordered)

    const float scaling = 0.125f;                      // 64^-0.5
    dim3 gProj(EE / 64, (BB * TT) / 128);              // (8, 64)

    proj_gemm<<<gProj, 256, 0, stream>>>(query, Wq, bq, qp, scaling);
    proj_gemm<<<gProj, 256, 0, stream>>>(key,   Wk, bk, kp, 1.0f);
    proj_gemm<<<gProj, 256, 0, stream>>>(value, Wv, bv, vp, 1.0f);

    scores_kernel<<<dim3(SS / 64, TT / 64, BB * HH), 256, 0, stream>>>(
        qp, kp, am, kpm, attnW);
    softmax_kernel<<<BB * HH * TT, 256, 0, stream>>>(attnW);
    pv_kernel<<<dim3(TT / 128, BB * HH), 256, 0, stream>>>(attnW, vp, ctx);

    proj_gemm<<<gProj, 256, 0, stream>>>(ctx, Wo, bo, out, 1.0f);
}

// Round 8
// 1297.648 us; speedup vs baseline: 1.1179x; 1.1179x over previous
//
#include <hip/hip_runtime.h>
#include <stdint.h>

#define BB 4
#define TT 2048
#define SS 2048
#define EE 512
#define HH 8
#define DH 64
#define NEG_INF_F (-1e30f)

using short8 = __attribute__((ext_vector_type(8))) short;
using f32x4  = __attribute__((ext_vector_type(4))) float;

__device__ __forceinline__ unsigned short f2bf(float f) {
    unsigned int u = __float_as_uint(f);
    unsigned int r = (u + 0x7FFFu + ((u >> 16) & 1u)) >> 16;
    return (unsigned short)r;
}
__device__ __forceinline__ unsigned int pack2(float a, float b) {
    return (unsigned int)f2bf(a) | ((unsigned int)f2bf(b) << 16);
}
__device__ __forceinline__ short8 cvt_frag(float4 a, float4 b) {
    short8 r;
    r[0] = (short)f2bf(a.x); r[1] = (short)f2bf(a.y);
    r[2] = (short)f2bf(a.z); r[3] = (short)f2bf(a.w);
    r[4] = (short)f2bf(b.x); r[5] = (short)f2bf(b.y);
    r[6] = (short)f2bf(b.z); r[7] = (short)f2bf(b.w);
    return r;
}

// Stage a 64x64 f32 tile (row_stride elems) -> bf16 LDS [64][72] (pad 8 => 16B-aligned rows)
__device__ __forceinline__ void stage_tile_bf16(const float* src_base, size_t row_stride,
        unsigned short (*dst)[72], int tid) {
    const int row = tid >> 2;
    const int cg  = (tid & 3) * 16;
    const float4* s4 = reinterpret_cast<const float4*>(src_base + (size_t)row * row_stride + cg);
    float4 a = s4[0], b = s4[1], c = s4[2], d = s4[3];
    uint4* d4 = reinterpret_cast<uint4*>(&dst[row][cg]);
    d4[0] = make_uint4(pack2(a.x, a.y), pack2(a.z, a.w), pack2(b.x, b.y), pack2(b.z, b.w));
    d4[1] = make_uint4(pack2(c.x, c.y), pack2(c.z, c.w), pack2(d.x, d.y), pack2(d.z, d.w));
}

// ---------------------------------------------------------------------------
// fp32 projection GEMM (unchanged anchor): C[M,512]=(A@W+bias)*alpha
// ---------------------------------------------------------------------------
__global__ __launch_bounds__(256) void proj_gemm(const float* __restrict__ A,
        const float* __restrict__ W, const float* __restrict__ bias,
        float* __restrict__ C, float alpha) {
    const int K = EE, N = EE;
    __shared__ float As[16][128 + 4];
    __shared__ float Bs[16][64 + 4];
    const int tid = threadIdx.x;
    const int tx = tid & 15, ty = tid >> 4;
    const int bm = blockIdx.y * 128, bn = blockIdx.x * 64;
    float acc[8][4] = {};
    for (int k0 = 0; k0 < K; k0 += 16) {
        #pragma unroll
        for (int j = 0; j < 2; ++j) {
            int f = tid + 256 * j;
            int row = f >> 2, c4 = f & 3;
            float4 v = *reinterpret_cast<const float4*>(&A[(size_t)(bm + row) * K + k0 + c4 * 4]);
            As[c4 * 4 + 0][row] = v.x; As[c4 * 4 + 1][row] = v.y;
            As[c4 * 4 + 2][row] = v.z; As[c4 * 4 + 3][row] = v.w;
        }
        {
            int row = tid >> 4, c4 = tid & 15;
            float4 v = *reinterpret_cast<const float4*>(&W[(size_t)(k0 + row) * N + bn + c4 * 4]);
            *reinterpret_cast<float4*>(&Bs[row][c4 * 4]) = v;
        }
        __syncthreads();
        #pragma unroll
        for (int kk = 0; kk < 16; ++kk) {
            float a[8], b[4];
            #pragma unroll
            for (int i = 0; i < 8; ++i) a[i] = As[kk][ty * 8 + i];
            #pragma unroll
            for (int j = 0; j < 4; ++j) b[j] = Bs[kk][tx * 4 + j];
            #pragma unroll
            for (int i = 0; i < 8; ++i)
                #pragma unroll
                for (int j = 0; j < 4; ++j)
                    acc[i][j] = fmaf(a[i], b[j], acc[i][j]);
        }
        __syncthreads();
    }
    #pragma unroll
    for (int i = 0; i < 8; ++i) {
        float4 o;
        o.x = (acc[i][0] + bias[bn + tx * 4 + 0]) * alpha;
        o.y = (acc[i][1] + bias[bn + tx * 4 + 1]) * alpha;
        o.z = (acc[i][2] + bias[bn + tx * 4 + 2]) * alpha;
        o.w = (acc[i][3] + bias[bn + tx * 4 + 3]) * alpha;
        *reinterpret_cast<float4*>(&C[(size_t)(bm + ty * 8 + i) * N + bn + tx * 4]) = o;
    }
}

// ---------------------------------------------------------------------------
// Value projection with transposed output: vpT[b][e=h*64+d][s] = (value@Wv+bv)
// ---------------------------------------------------------------------------
__global__ __launch_bounds__(256) void proj_gemm_vT(const float* __restrict__ A,
        const float* __restrict__ W, const float* __restrict__ bias,
        float* __restrict__ vpT) {
    const int K = EE, N = EE;
    __shared__ float As[16][128 + 4];
    __shared__ float Bs[16][64 + 4];
    const int tid = threadIdx.x;
    const int tx = tid & 15, ty = tid >> 4;
    const int bm = blockIdx.y * 128, bn = blockIdx.x * 64;
    float acc[8][4] = {};
    for (int k0 = 0; k0 < K; k0 += 16) {
        #pragma unroll
        for (int j = 0; j < 2; ++j) {
            int f = tid + 256 * j;
            int row = f >> 2, c4 = f & 3;
            float4 v = *reinterpret_cast<const float4*>(&A[(size_t)(bm + row) * K + k0 + c4 * 4]);
            As[c4 * 4 + 0][row] = v.x; As[c4 * 4 + 1][row] = v.y;
            As[c4 * 4 + 2][row] = v.z; As[c4 * 4 + 3][row] = v.w;
        }
        {
            int row = tid >> 4, c4 = tid & 15;
            float4 v = *reinterpret_cast<const float4*>(&W[(size_t)(k0 + row) * N + bn + c4 * 4]);
            *reinterpret_cast<float4*>(&Bs[row][c4 * 4]) = v;
        }
        __syncthreads();
        #pragma unroll
        for (int kk = 0; kk < 16; ++kk) {
            float a[8], b[4];
            #pragma unroll
            for (int i = 0; i < 8; ++i) a[i] = As[kk][ty * 8 + i];
            #pragma unroll
            for (int j = 0; j < 4; ++j) b[j] = Bs[kk][tx * 4 + j];
            #pragma unroll
            for (int i = 0; i < 8; ++i)
                #pragma unroll
                for (int j = 0; j < 4; ++j)
                    acc[i][j] = fmaf(a[i], b[j], acc[i][j]);
        }
        __syncthreads();
    }
    // transposed epilogue: row m = b*SS+s, col n=e  ->  vpT[(b*EE+n)*SS + s]
    const int bb = bm >> 11;                 // SS = 2048
    const int sb = (bm & (SS - 1)) + ty * 8;
    #pragma unroll
    for (int j = 0; j < 4; ++j) {
        const int n = bn + tx * 4 + j;
        const float bvj = bias[n];
        float4 o0 = make_float4(acc[0][j] + bvj, acc[1][j] + bvj, acc[2][j] + bvj, acc[3][j] + bvj);
        float4 o1 = make_float4(acc[4][j] + bvj, acc[5][j] + bvj, acc[6][j] + bvj, acc[7][j] + bvj);
        float* dst = &vpT[((size_t)bb * EE + n) * SS + sb];
        *reinterpret_cast<float4*>(dst) = o0;
        *reinterpret_cast<float4*>(dst + 4) = o1;
    }
}

// ---------------------------------------------------------------------------
// Fused QK^T + mask + softmax -> writes final attn_weights (fp32), bf16 MFMA.
// Block: (bh, 64 t-rows). 4 waves x 16 rows. Two passes over 32 K-tiles:
//   pass 1: online (m,l) only; pass 2: recompute scores, P=exp(s-m)/l, store.
// ---------------------------------------------------------------------------
__global__ __launch_bounds__(256) void flash_scores(const float* __restrict__ qp,
        const float* __restrict__ kp, const uint8_t* __restrict__ am,
        const uint8_t* __restrict__ kpm, float* __restrict__ attnW) {
    const int bh = blockIdx.y;
    const int b = bh >> 3, h = bh & 7;
    const int t0 = blockIdx.x * 64;
    __shared__ unsigned short Ks[64][72];
    const int tid = threadIdx.x;
    const int lane = tid & 63, wid = tid >> 6;
    const int lc = lane & 15, lg = lane >> 4;

    // Q fragments, direct from global (per-wave-exclusive rows)
    short8 aq[2];
    {
        const float* qrow = &qp[(size_t)(b * TT + t0 + wid * 16 + lc) * EE + h * DH];
        #pragma unroll
        for (int kc = 0; kc < 2; ++kc) {
            float4 f0 = *reinterpret_cast<const float4*>(qrow + kc * 32 + lg * 8);
            float4 f1 = *reinterpret_cast<const float4*>(qrow + kc * 32 + lg * 8 + 4);
            aq[kc] = cvt_frag(f0, f1);
        }
    }
    const int trow = t0 + wid * 16 + lg * 4;   // + r -> global t of C-layout rows
    float mrun[4], lrun[4];
    #pragma unroll
    for (int r = 0; r < 4; ++r) { mrun[r] = -3.0e38f; lrun[r] = 0.0f; }

    // ---------------- pass 1: m, l ----------------
    for (int st = 0; st < 32; ++st) {
        const int s0 = st * 64;
        stage_tile_bf16(&kp[(size_t)(b * SS + s0) * EE + h * DH], EE, Ks, tid);
        __syncthreads();
        float sv[4][4];
        float tmax[4];
        #pragma unroll
        for (int r = 0; r < 4; ++r) tmax[r] = -3.0e38f;
        #pragma unroll
        for (int ct = 0; ct < 4; ++ct) {
            const int brow = ct * 16 + lc;
            short8 b0 = *reinterpret_cast<const short8*>(&Ks[brow][lg * 8]);
            short8 b1 = *reinterpret_cast<const short8*>(&Ks[brow][32 + lg * 8]);
            f32x4 c = {0.0f, 0.0f, 0.0f, 0.0f};
            c = __builtin_amdgcn_mfma_f32_16x16x32_bf16(aq[0], b0, c, 0, 0, 0);
            c = __builtin_amdgcn_mfma_f32_16x16x32_bf16(aq[1], b1, c, 0, 0, 0);
            const int s = s0 + ct * 16 + lc;
            const bool kpb = kpm[b * SS + s] != 0;
            #pragma unroll
            for (int r = 0; r < 4; ++r) {
                const bool mk = kpb || (am[(size_t)(trow + r) * SS + s] != 0);
                const float scv = mk ? NEG_INF_F : c[r];
                sv[ct][r] = scv;
                tmax[r] = fmaxf(tmax[r], scv);
            }
        }
        __syncthreads();
        #pragma unroll
        for (int r = 0; r < 4; ++r) {
            #pragma unroll
            for (int mm = 8; mm >= 1; mm >>= 1)
                tmax[r] = fmaxf(tmax[r], __shfl_xor(tmax[r], mm, 16));
        }
        float ts[4] = {0.0f, 0.0f, 0.0f, 0.0f};
        #pragma unroll
        for (int ct = 0; ct < 4; ++ct)
            #pragma unroll
            for (int r = 0; r < 4; ++r) {
                const float mnew = fmaxf(mrun[r], tmax[r]);
                ts[r] += __expf(sv[ct][r] - mnew);
            }
        #pragma unroll
        for (int r = 0; r < 4; ++r) {
            const float mnew = fmaxf(mrun[r], tmax[r]);
            #pragma unroll
            for (int mm = 8; mm >= 1; mm >>= 1)
                ts[r] += __shfl_xor(ts[r], mm, 16);
            lrun[r] = lrun[r] * __expf(mrun[r] - mnew) + ts[r];
            mrun[r] = mnew;
        }
    }
    float linv[4];
    #pragma unroll
    for (int r = 0; r < 4; ++r) linv[r] = 1.0f / lrun[r];

    // ---------------- pass 2: P = exp(s-m)/l, store ----------------
    for (int st = 0; st < 32; ++st) {
        const int s0 = st * 64;
        stage_tile_bf16(&kp[(size_t)(b * SS + s0) * EE + h * DH], EE, Ks, tid);
        __syncthreads();
        #pragma unroll
        for (int ct = 0; ct < 4; ++ct) {
            const int brow = ct * 16 + lc;
            short8 b0 = *reinterpret_cast<const short8*>(&Ks[brow][lg * 8]);
            short8 b1 = *reinterpret_cast<const short8*>(&Ks[brow][32 + lg * 8]);
            f32x4 c = {0.0f, 0.0f, 0.0f, 0.0f};
            c = __builtin_amdgcn_mfma_f32_16x16x32_bf16(aq[0], b0, c, 0, 0, 0);
            c = __builtin_amdgcn_mfma_f32_16x16x32_bf16(aq[1], b1, c, 0, 0, 0);
            const int s = s0 + ct * 16 + lc;
            const bool kpb = kpm[b * SS + s] != 0;
            #pragma unroll
            for (int r = 0; r < 4; ++r) {
                const bool mk = kpb || (am[(size_t)(trow + r) * SS + s] != 0);
                const float scv = mk ? NEG_INF_F : c[r];
                const float p = __expf(scv - mrun[r]) * linv[r];
                attnW[((size_t)bh * TT + trow + r) * SS + s] = p;
            }
        }
        __syncthreads();
    }
}

// ---------------------------------------------------------------------------
// ctx[b,t,h*64+d] = sum_s P[bh,t,s] * v[b,s,h*64+d]; bf16 MFMA.
// P fragments direct from global (per-wave rows, full-line coverage);
// V^T tile staged via LDS from vpT[b][h*64+d][s].
// ---------------------------------------------------------------------------
__global__ __launch_bounds__(256) void pv_mfma(const float* __restrict__ P,
        const float* __restrict__ vpT, float* __restrict__ ctx) {
    const int bh = blockIdx.y;
    const int b = bh >> 3, h = bh & 7;
    const int t0 = blockIdx.x * 64;
    __shared__ unsigned short Vt[64][72];
    const int tid = threadIdx.x;
    const int lane = tid & 63, wid = tid >> 6;
    const int lc = lane & 15, lg = lane >> 4;

    f32x4 acc[4];
    #pragma unroll
    for (int ct = 0; ct < 4; ++ct) acc[ct] = (f32x4){0.0f, 0.0f, 0.0f, 0.0f};

    const float* prow = &P[((size_t)bh * TT + t0 + wid * 16 + lc) * SS];

    for (int st = 0; st < 32; ++st) {
        const int s0 = st * 64;
        stage_tile_bf16(&vpT[((size_t)b * EE + h * DH) * SS + s0], SS, Vt, tid);
        __syncthreads();
        short8 ap[2];
        #pragma unroll
        for (int kc = 0; kc < 2; ++kc) {
            float4 f0 = *reinterpret_cast<const float4*>(prow + s0 + kc * 32 + lg * 8);
            float4 f1 = *reinterpret_cast<const float4*>(prow + s0 + kc * 32 + lg * 8 + 4);
            ap[kc] = cvt_frag(f0, f1);
        }
        #pragma unroll
        for (int ct = 0; ct < 4; ++ct) {
            const int brow = ct * 16 + lc;
            short8 b0 = *reinterpret_cast<const short8*>(&Vt[brow][lg * 8]);
            short8 b1 = *reinterpret_cast<const short8*>(&Vt[brow][32 + lg * 8]);
            acc[ct] = __builtin_amdgcn_mfma_f32_16x16x32_bf16(ap[0], b0, acc[ct], 0, 0, 0);
            acc[ct] = __builtin_amdgcn_mfma_f32_16x16x32_bf16(ap[1], b1, acc[ct], 0, 0, 0);
        }
        __syncthreads();
    }
    const int trow = t0 + wid * 16 + lg * 4;
    #pragma unroll
    for (int ct = 0; ct < 4; ++ct)
        #pragma unroll
        for (int r = 0; r < 4; ++r)
            ctx[(size_t)(b * TT + trow + r) * EE + h * DH + ct * 16 + lc] = acc[ct][r];
}

// ---------------------------------------------------------------------------
extern "C" void kernel_launch(void* const* d_in, const int* in_sizes, int n_in,
                              void* d_out, int out_size, void* d_ws, size_t ws_size,
                              hipStream_t stream) {
    const float*   query = (const float*)d_in[0];
    const float*   key   = (const float*)d_in[1];
    const float*   value = (const float*)d_in[2];
    const uint8_t* kpm   = (const uint8_t*)d_in[3];
    const uint8_t* am    = (const uint8_t*)d_in[4];
    const float* Wq = (const float*)d_in[5];  const float* bq = (const float*)d_in[6];
    const float* Wk = (const float*)d_in[7];  const float* bk = (const float*)d_in[8];
    const float* Wv = (const float*)d_in[9];  const float* bv = (const float*)d_in[10];
    const float* Wo = (const float*)d_in[11]; const float* bo = (const float*)d_in[12];

    float* out   = (float*)d_out;
    const size_t BTE = (size_t)BB * TT * EE;           // 4,194,304
    float* attnW = out + BTE;                          // [B,H,T,S]
    float* ws  = (float*)d_ws;
    float* qp  = ws;                                   // [B,T,E]
    float* kp  = ws + BTE;                             // [B,S,E]
    float* vpT = ws + 2 * BTE;                         // [B,E,S] (per-b transposed V-proj)
    float* ctx = qp;  // alias: qp dead after flash_scores (stream-ordered)

    const float scaling = 0.125f;                      // 64^-0.5
    dim3 gProj(EE / 64, (BB * TT) / 128);              // (8, 64)

    proj_gemm   <<<gProj, 256, 0, stream>>>(query, Wq, bq, qp, scaling);
    proj_gemm   <<<gProj, 256, 0, stream>>>(key,   Wk, bk, kp, 1.0f);
    proj_gemm_vT<<<gProj, 256, 0, stream>>>(value, Wv, bv, vpT);

    flash_scores<<<dim3(TT / 64, BB * HH), 256, 0, stream>>>(qp, kp, am, kpm, attnW);
    pv_mfma     <<<dim3(TT / 64, BB * HH), 256, 0, stream>>>(attnW, vpT, ctx);

    proj_gemm   <<<gProj, 256, 0, stream>>>(ctx, Wo, bo, out, 1.0f);
}